// Round 3
// baseline (296.468 us; speedup 1.0000x reference)
//
#include <hip/hip_runtime.h>
#include <stdint.h>

#define NROWS 8192
#define BHALF 4096
#define DIM 512
#define NB2 32             // 8192/256 row-blocks
#define NTRI2 528          // 32*33/2 upper-triangle blocks
#define NRIDER 64          // colstats rider blocks

typedef __attribute__((ext_vector_type(8))) short bf16x8;
typedef __attribute__((ext_vector_type(4))) float f32x4;

__device__ __forceinline__ unsigned short f32_to_bf16(float f) {
  uint32_t u = __float_as_uint(f);
  u += 0x7fffu + ((u >> 16) & 1u);
  return (unsigned short)(u >> 16);
}
__device__ __forceinline__ float bf16_to_f32(unsigned short h) {
  return __uint_as_float(((uint32_t)h) << 16);
}

__device__ __forceinline__ void gload_lds16(const void* g, void* l) {
  __builtin_amdgcn_global_load_lds(
      (const __attribute__((address_space(1))) unsigned int*)g,
      (__attribute__((address_space(3))) unsigned int*)l, 16, 0, 0);
}

// ---------------- fused prep: norms, bf16 hi/lo split, trace, pos_sim ----------------
extern "C" __global__ __launch_bounds__(256) void k_prep(
    const float* __restrict__ za, const float* __restrict__ zp,
    unsigned short* __restrict__ zhi, unsigned short* __restrict__ zlo,
    float* __restrict__ inv_norms, float* __restrict__ scalars)
{
  __shared__ float tr_sh[4], pd_sh[4];
  const int wid = threadIdx.x >> 6, lane = threadIdx.x & 63;
  const int i = blockIdx.x * 4 + wid;                 // pair index in [0,4096)
  const float4* a4 = (const float4*)(za + (size_t)i * DIM);
  const float4* p4 = (const float4*)(zp + (size_t)i * DIM);
  float4 a0 = a4[lane * 2], a1 = a4[lane * 2 + 1];
  float4 p0 = p4[lane * 2], p1 = p4[lane * 2 + 1];
  float xa[8] = {a0.x, a0.y, a0.z, a0.w, a1.x, a1.y, a1.z, a1.w};
  float xp[8] = {p0.x, p0.y, p0.z, p0.w, p1.x, p1.y, p1.z, p1.w};
  float ssa = 0.f, ssp = 0.f;
#pragma unroll
  for (int j = 0; j < 8; ++j) { ssa += xa[j] * xa[j]; ssp += xp[j] * xp[j]; }
#pragma unroll
  for (int m = 1; m < 64; m <<= 1) {
    ssa += __shfl_xor(ssa, m, 64);
    ssp += __shfl_xor(ssp, m, 64);
  }
  float na = fmaxf(sqrtf(ssa), 1e-8f), np_ = fmaxf(sqrtf(ssp), 1e-8f);
  float ia = 1.0f / na, ip = 1.0f / np_;
  float pd = 0.f;
  unsigned short ha[8], la[8], hp[8], lp[8];
#pragma unroll
  for (int j = 0; j < 8; ++j) {
    float zna = xa[j] * ia, znp = xp[j] * ip;
    pd += zna * znp;
    ha[j] = f32_to_bf16(zna); la[j] = f32_to_bf16(zna - bf16_to_f32(ha[j]));
    hp[j] = f32_to_bf16(znp); lp[j] = f32_to_bf16(znp - bf16_to_f32(hp[j]));
  }
#pragma unroll
  for (int m = 1; m < 64; m <<= 1) pd += __shfl_xor(pd, m, 64);
  float tr = ssa * ia * ia + ssp * ip * ip;
  if (lane == 0) {
    tr_sh[wid] = tr; pd_sh[wid] = pd;
    inv_norms[i] = ia; inv_norms[i + BHALF] = ip;
  }
  uint4 hva = {(uint32_t)ha[0] | ((uint32_t)ha[1] << 16), (uint32_t)ha[2] | ((uint32_t)ha[3] << 16),
               (uint32_t)ha[4] | ((uint32_t)ha[5] << 16), (uint32_t)ha[6] | ((uint32_t)ha[7] << 16)};
  uint4 lva = {(uint32_t)la[0] | ((uint32_t)la[1] << 16), (uint32_t)la[2] | ((uint32_t)la[3] << 16),
               (uint32_t)la[4] | ((uint32_t)la[5] << 16), (uint32_t)la[6] | ((uint32_t)la[7] << 16)};
  uint4 hvp = {(uint32_t)hp[0] | ((uint32_t)hp[1] << 16), (uint32_t)hp[2] | ((uint32_t)hp[3] << 16),
               (uint32_t)hp[4] | ((uint32_t)hp[5] << 16), (uint32_t)hp[6] | ((uint32_t)hp[7] << 16)};
  uint4 lvp = {(uint32_t)lp[0] | ((uint32_t)lp[1] << 16), (uint32_t)lp[2] | ((uint32_t)lp[3] << 16),
               (uint32_t)lp[4] | ((uint32_t)lp[5] << 16), (uint32_t)lp[6] | ((uint32_t)lp[7] << 16)};
  ((uint4*)(zhi + (size_t)i * DIM))[lane] = hva;
  ((uint4*)(zlo + (size_t)i * DIM))[lane] = lva;
  ((uint4*)(zhi + (size_t)(i + BHALF) * DIM))[lane] = hvp;
  ((uint4*)(zlo + (size_t)(i + BHALF) * DIM))[lane] = lvp;
  __syncthreads();
  if (threadIdx.x == 0) {
    atomicAdd(&scalars[0], tr_sh[0] + tr_sh[1] + tr_sh[2] + tr_sh[3]);
    atomicAdd(&scalars[1], pd_sh[0] + pd_sh[1] + pd_sh[2] + pd_sh[3]);
  }
}

// ---------------- main fused kernel: riders (colstats) + 256^2 8-phase GEMM ----------------
extern "C" __global__ __launch_bounds__(512, 2) void k_gemm(
    const unsigned short* __restrict__ wsbase,   // zhi at 0, zlo at NROWS*DIM elems
    const float* __restrict__ za, const float* __restrict__ zp,
    const float* __restrict__ inv_norms,
    float* __restrict__ sumexp, unsigned long long* __restrict__ amax,
    float* __restrict__ colsum, float* __restrict__ colsumsq,
    float* __restrict__ snorm)
{
  __shared__ char lds[2 * 65536] __attribute__((aligned(128)));

  // ---- rider blocks: column stats, overlapped with GEMM ----
  if (blockIdx.x < NRIDER) {
    const int c = threadIdx.x;          // 512 threads = 512 columns
    const int r0 = blockIdx.x * 128;
    const float* src = (r0 < BHALF) ? (za + (size_t)r0 * DIM)
                                    : (zp + (size_t)(r0 - BHALF) * DIM);
    float s = 0.f, q = 0.f, nm = 0.f;
#pragma unroll 4
    for (int rr = 0; rr < 128; ++rr) {
      float v = src[(size_t)rr * DIM + c];
      float inv = inv_norms[r0 + rr];
      s += v; q += v * v; nm += v * inv;
    }
    atomicAdd(&colsum[c], s);
    atomicAdd(&colsumsq[c], q);
    atomicAdd(&snorm[c], nm);
    return;
  }

  const int tid = threadIdx.x;
  const int w = tid >> 6, lane = tid & 63;
  const int wr = w >> 2, wc = w & 3;                 // 2x4 wave grid
  const int fr = lane & 15, slot0 = lane >> 4, fq = lane >> 4;

  // XCD-bijective swizzle: XCD k (= blockIdx%8) gets 66 consecutive triangle blocks
  const int raw = blockIdx.x - NRIDER;               // 0..527
  int t = (raw % 8) * 66 + raw / 8;
  // triangular decode t -> (bi, bj), bi <= bj
  int bi = (int)(32.5f - sqrtf(32.5f * 32.5f - 2.0f * (float)t));
  if (bi < 0) bi = 0;
  if (bi > 31) bi = 31;
  while (bi > 0 && (bi * NB2 - bi * (bi - 1) / 2) > t) --bi;
  while (bi < 31 && ((bi + 1) * NB2 - (bi + 1) * bi / 2) <= t) ++bi;
  const int bj = bi + (t - (bi * NB2 - bi * (bi - 1) / 2));
  const int rowA = bi * 256, rowB = bj * 256;

  // ---- per-lane global source offsets for the 8 staging chunks ----
  // LDS buffer layout (64KB): [Ahi 16K][Alo 16K][Bhi 16K][Blo 16K], each [256][32] bf16
  // physical byte = logical ^ (((row>>1)&3)<<4)   (involution, slot bits 5:4)
  uint32_t goff[8];
#pragma unroll
  for (int s = 0; s < 8; ++s) {
    int c = w * 8 + s;                  // chunk 0..63 (1KB each)
    int p = c >> 4;                     // panel 0..3
    int offp = (c & 15) * 1024 + lane * 16;   // physical byte within panel
    int r = offp >> 6;
    int L = offp ^ (((r >> 1) & 3) << 4);     // logical byte
    int cb = L & 63;
    uint32_t rowg = (uint32_t)(((p & 2) ? rowB : rowA) + r);
    uint32_t arr = (p & 1) ? (uint32_t)(NROWS * DIM) : 0u;   // zlo elem offset
    goff[s] = arr + rowg * DIM + (uint32_t)(cb >> 1);
  }

  // ds_read base offsets (panel-relative, swizzled)
  const int r0A = wr * 128 + fr;
  const int aoff = r0A * 64 + ((slot0 ^ ((r0A >> 1) & 3)) << 4);
  const int r0B = wc * 64 + fr;
  const int boff = r0B * 64 + ((slot0 ^ ((r0B >> 1) & 3)) << 4);

  f32x4 acc[8][4];
#pragma unroll
  for (int m = 0; m < 8; ++m)
#pragma unroll
    for (int n = 0; n < 4; ++n) acc[m][n] = (f32x4){0.f, 0.f, 0.f, 0.f};

  // ---- prologue: stage K-step 0 into buf 0 ----
  {
    char* Dw = lds + w * 8192;
#pragma unroll
    for (int s = 0; s < 8; ++s)
      gload_lds16(wsbase + goff[s], Dw + s * 1024);
  }
  asm volatile("s_waitcnt vmcnt(0)" ::: "memory");
  __builtin_amdgcn_s_barrier();

  // ---- main K loop: 16 steps of BK=32, 2 phases each ----
  for (int kt = 0; kt < 16; ++kt) {
    const char* Lb = lds + (kt & 1) * 65536;
    bf16x8 ah[4], al[4], bh[4], bl[4];
    // phase 0: ds_read A[0..3] + B[0..3] (hi,lo); issue next-step stage
#pragma unroll
    for (int n = 0; n < 4; ++n) {
      bh[n] = *(const bf16x8*)(Lb + 32768 + boff + n * 1024);
      bl[n] = *(const bf16x8*)(Lb + 49152 + boff + n * 1024);
    }
#pragma unroll
    for (int m = 0; m < 4; ++m) {
      ah[m] = *(const bf16x8*)(Lb + aoff + m * 1024);
      al[m] = *(const bf16x8*)(Lb + 16384 + aoff + m * 1024);
    }
    if (kt < 15) {
      char* Dw = lds + ((kt & 1) ^ 1) * 65536 + w * 8192;
      uint32_t ko = (uint32_t)(kt + 1) * 32;
#pragma unroll
      for (int s = 0; s < 8; ++s)
        gload_lds16(wsbase + goff[s] + ko, Dw + s * 1024);
    }
    __builtin_amdgcn_s_barrier();
    asm volatile("s_waitcnt lgkmcnt(0)" ::: "memory");
    __builtin_amdgcn_s_setprio(1);
#pragma unroll
    for (int m = 0; m < 4; ++m)
#pragma unroll
      for (int n = 0; n < 4; ++n) {
        acc[m][n] = __builtin_amdgcn_mfma_f32_16x16x32_bf16(ah[m], bh[n], acc[m][n], 0, 0, 0);
        acc[m][n] = __builtin_amdgcn_mfma_f32_16x16x32_bf16(ah[m], bl[n], acc[m][n], 0, 0, 0);
        acc[m][n] = __builtin_amdgcn_mfma_f32_16x16x32_bf16(al[m], bh[n], acc[m][n], 0, 0, 0);
      }
    __builtin_amdgcn_s_setprio(0);
    __builtin_amdgcn_s_barrier();
    // phase 1: ds_read A[4..7]
#pragma unroll
    for (int m = 0; m < 4; ++m) {
      ah[m] = *(const bf16x8*)(Lb + aoff + (4 + m) * 1024);
      al[m] = *(const bf16x8*)(Lb + 16384 + aoff + (4 + m) * 1024);
    }
    __builtin_amdgcn_s_barrier();
    asm volatile("s_waitcnt lgkmcnt(0)" ::: "memory");
    __builtin_amdgcn_s_setprio(1);
#pragma unroll
    for (int m = 0; m < 4; ++m)
#pragma unroll
      for (int n = 0; n < 4; ++n) {
        acc[4 + m][n] = __builtin_amdgcn_mfma_f32_16x16x32_bf16(ah[m], bh[n], acc[4 + m][n], 0, 0, 0);
        acc[4 + m][n] = __builtin_amdgcn_mfma_f32_16x16x32_bf16(ah[m], bl[n], acc[4 + m][n], 0, 0, 0);
        acc[4 + m][n] = __builtin_amdgcn_mfma_f32_16x16x32_bf16(al[m], bh[n], acc[4 + m][n], 0, 0, 0);
      }
    __builtin_amdgcn_s_setprio(0);
    if (kt < 15) asm volatile("s_waitcnt vmcnt(0)" ::: "memory");
    __builtin_amdgcn_s_barrier();
  }

  // ---- epilogue ----
  // row-side: rows gi in A-panel (this wave's 128-row half), reduce over fr lanes + n
#pragma unroll
  for (int m = 0; m < 8; ++m) {
#pragma unroll
    for (int rr = 0; rr < 4; ++rr) {
      int gi = rowA + wr * 128 + m * 16 + fq * 4 + rr;
      float se = 0.f;
      unsigned long long best = 0ull;
#pragma unroll
      for (int n = 0; n < 4; ++n) {
        int gj = rowB + wc * 64 + n * 16 + fr;
        if (gi != gj) {
          float logit = 2.0f * acc[m][n][rr];   // /T with T=0.5
          se += __expf(logit);
          uint32_t bu = __float_as_uint(logit);
          uint32_t sk = (bu & 0x80000000u) ? ~bu : (bu | 0x80000000u);
          unsigned long long pk =
              ((unsigned long long)sk << 32) | (uint32_t)(~(uint32_t)gj);
          if (pk > best) best = pk;
        }
      }
#pragma unroll
      for (int msk = 1; msk < 16; msk <<= 1) {
        se += __shfl_xor(se, msk, 64);
        unsigned long long o = __shfl_xor(best, msk, 64);
        if (o > best) best = o;
      }
      if (fr == 0) {
        atomicAdd(&sumexp[gi], se);
        atomicMax(&amax[gi], best);
      }
    }
  }

  // col-side (off-diagonal only): rows gj in B-panel via cos^T = cos
  if (bi != bj) {
#pragma unroll
    for (int n = 0; n < 4; ++n) {
      int gj = rowB + wc * 64 + n * 16 + fr;
      float se = 0.f;
      unsigned long long best = 0ull;
#pragma unroll
      for (int m = 0; m < 8; ++m) {
#pragma unroll
        for (int rr = 0; rr < 4; ++rr) {
          int gi = rowA + wr * 128 + m * 16 + fq * 4 + rr;
          float logit = 2.0f * acc[m][n][rr];
          se += __expf(logit);
          uint32_t bu = __float_as_uint(logit);
          uint32_t sk = (bu & 0x80000000u) ? ~bu : (bu | 0x80000000u);
          unsigned long long pk =
              ((unsigned long long)sk << 32) | (uint32_t)(~(uint32_t)gi);
          if (pk > best) best = pk;
        }
      }
#pragma unroll
      for (int msk = 16; msk < 64; msk <<= 1) {
        se += __shfl_xor(se, msk, 64);
        unsigned long long o = __shfl_xor(best, msk, 64);
        if (o > best) best = o;
      }
      if (fq == 0) {
        atomicAdd(&sumexp[gj], se);
        atomicMax(&amax[gj], best);
      }
    }
  }
}

// ---------------- final combine ----------------
extern "C" __global__ __launch_bounds__(1024) void k_final(
    const float* __restrict__ sumexp, const unsigned long long* __restrict__ amax,
    const float* __restrict__ colsum, const float* __restrict__ colsumsq,
    const float* __restrict__ snorm, const float* __restrict__ scalars,
    float* __restrict__ out)
{
  __shared__ double red[1024];
  const int t = threadIdx.x;
  double lsesum = 0.0, cnt = 0.0;
  for (int r = t; r < NROWS; r += 1024) {
    lsesum += log((double)sumexp[r]);
    int label = (r < BHALF) ? r + BHALF : r - BHALF;
    unsigned int idx = ~(unsigned int)(amax[r] & 0xffffffffull);
    if ((int)idx == label) cnt += 1.0;
  }
  double stdsum = 0, mn2 = 0, sn2 = 0;
  for (int c = t; c < DIM; c += 1024) {
    double su = colsum[c], sq = colsumsq[c];
    double var = (sq - su * su / 8192.0) / 8191.0;
    stdsum += sqrt(var > 0.0 ? var : 0.0);
    double m = su / 8192.0; mn2 += m * m;
    double s = snorm[c];   sn2 += s * s;
  }
  auto red_sum = [&](double v) -> double {
    __syncthreads();
    red[t] = v; __syncthreads();
    for (int s = 512; s > 0; s >>= 1) {
      if (t < s) red[t] += red[t + s];
      __syncthreads();
    }
    return red[0];
  };
  double Tlse = red_sum(lsesum);
  double Tcnt = red_sum(cnt);
  double Tstd = red_sum(stdsum);
  double Tmn2 = red_sum(mn2);
  double Tsn2 = red_sum(sn2);
  if (t == 0) {
    double trace = scalars[0], posdot = scalars[1];
    double pos_sim = posdot / 4096.0;
    out[0] = (float)(Tlse / 8192.0 - 2.0 * pos_sim);
    out[1] = (float)(Tcnt / 8192.0);
    out[2] = (float)pos_sim;
    out[3] = (float)((Tsn2 - trace) / (8192.0 * 8191.0));
    out[4] = (float)(Tstd / 512.0);
    out[5] = (float)sqrt(Tmn2);
  }
}

extern "C" void kernel_launch(void* const* d_in, const int* in_sizes, int n_in,
                              void* d_out, int out_size, void* d_ws, size_t ws_size,
                              hipStream_t stream) {
  const float* za = (const float*)d_in[0];
  const float* zp = (const float*)d_in[1];
  float* out = (float*)d_out;
  char* ws = (char*)d_ws;
  size_t off = 0;
  unsigned short* zhi = (unsigned short*)(ws + off); off += (size_t)NROWS * DIM * 2;
  unsigned short* zlo = (unsigned short*)(ws + off); off += (size_t)NROWS * DIM * 2;
  float* inv_norms = (float*)(ws + off); off += (size_t)NROWS * 4;
  char* zbase = ws + off;
  float* sumexp = (float*)(ws + off); off += (size_t)NROWS * 4;
  unsigned long long* amax = (unsigned long long*)(ws + off); off += (size_t)NROWS * 8;
  float* colsum = (float*)(ws + off); off += (size_t)DIM * 4;
  float* colsumsq = (float*)(ws + off); off += (size_t)DIM * 4;
  float* snorm = (float*)(ws + off); off += (size_t)DIM * 4;
  float* scalars = (float*)(ws + off); off += 64;
  size_t zsize = (size_t)((ws + off) - zbase);

  hipMemsetAsync(zbase, 0, zsize, stream);
  k_prep<<<dim3(1024), dim3(256), 0, stream>>>(za, zp, zhi, zlo, inv_norms, scalars);
  k_gemm<<<dim3(NTRI2 + NRIDER), dim3(512), 0, stream>>>(
      (const unsigned short*)ws, za, zp, inv_norms, sumexp, amax,
      colsum, colsumsq, snorm);
  k_final<<<dim3(1), dim3(1024), 0, stream>>>(sumexp, amax, colsum, colsumsq, snorm, scalars, out);
}

// Round 4
// 286.126 us; speedup vs baseline: 1.0361x; 1.0361x over previous
//
#include <hip/hip_runtime.h>
#include <stdint.h>

#define NROWS 8192
#define BHALF 4096
#define DIM 512
#define NBLK 64            // 8192/128 row-blocks
#define NTRI 2080          // 64*65/2 upper-triangle blocks (= 8 XCDs * 260)
#define NRIDER 64          // colstats rider blocks

typedef __attribute__((ext_vector_type(8))) short bf16x8;
typedef __attribute__((ext_vector_type(4))) float f32x4;

__device__ __forceinline__ unsigned short f32_to_bf16(float f) {
  uint32_t u = __float_as_uint(f);
  u += 0x7fffu + ((u >> 16) & 1u);
  return (unsigned short)(u >> 16);
}
__device__ __forceinline__ float bf16_to_f32(unsigned short h) {
  return __uint_as_float(((uint32_t)h) << 16);
}

__device__ __forceinline__ void gload_lds16(const void* g, void* l) {
  __builtin_amdgcn_global_load_lds(
      (const __attribute__((address_space(1))) unsigned int*)g,
      (__attribute__((address_space(3))) unsigned int*)l, 16, 0, 0);
}

// ---------------- fused prep: norms, bf16 hi/lo split, trace, pos_sim ----------------
extern "C" __global__ __launch_bounds__(256) void k_prep(
    const float* __restrict__ za, const float* __restrict__ zp,
    unsigned short* __restrict__ zhi, unsigned short* __restrict__ zlo,
    float* __restrict__ inv_norms, float* __restrict__ scalars)
{
  __shared__ float tr_sh[4], pd_sh[4];
  const int wid = threadIdx.x >> 6, lane = threadIdx.x & 63;
  const int i = blockIdx.x * 4 + wid;                 // pair index in [0,4096)
  const float4* a4 = (const float4*)(za + (size_t)i * DIM);
  const float4* p4 = (const float4*)(zp + (size_t)i * DIM);
  float4 a0 = a4[lane * 2], a1 = a4[lane * 2 + 1];
  float4 p0 = p4[lane * 2], p1 = p4[lane * 2 + 1];
  float xa[8] = {a0.x, a0.y, a0.z, a0.w, a1.x, a1.y, a1.z, a1.w};
  float xp[8] = {p0.x, p0.y, p0.z, p0.w, p1.x, p1.y, p1.z, p1.w};
  float ssa = 0.f, ssp = 0.f;
#pragma unroll
  for (int j = 0; j < 8; ++j) { ssa += xa[j] * xa[j]; ssp += xp[j] * xp[j]; }
#pragma unroll
  for (int m = 1; m < 64; m <<= 1) {
    ssa += __shfl_xor(ssa, m, 64);
    ssp += __shfl_xor(ssp, m, 64);
  }
  float na = fmaxf(sqrtf(ssa), 1e-8f), np_ = fmaxf(sqrtf(ssp), 1e-8f);
  float ia = 1.0f / na, ip = 1.0f / np_;
  float pd = 0.f;
  unsigned short ha[8], la[8], hp[8], lp[8];
#pragma unroll
  for (int j = 0; j < 8; ++j) {
    float zna = xa[j] * ia, znp = xp[j] * ip;
    pd += zna * znp;
    ha[j] = f32_to_bf16(zna); la[j] = f32_to_bf16(zna - bf16_to_f32(ha[j]));
    hp[j] = f32_to_bf16(znp); lp[j] = f32_to_bf16(znp - bf16_to_f32(hp[j]));
  }
#pragma unroll
  for (int m = 1; m < 64; m <<= 1) pd += __shfl_xor(pd, m, 64);
  float tr = ssa * ia * ia + ssp * ip * ip;
  if (lane == 0) {
    tr_sh[wid] = tr; pd_sh[wid] = pd;
    inv_norms[i] = ia; inv_norms[i + BHALF] = ip;
  }
  uint4 hva = {(uint32_t)ha[0] | ((uint32_t)ha[1] << 16), (uint32_t)ha[2] | ((uint32_t)ha[3] << 16),
               (uint32_t)ha[4] | ((uint32_t)ha[5] << 16), (uint32_t)ha[6] | ((uint32_t)ha[7] << 16)};
  uint4 lva = {(uint32_t)la[0] | ((uint32_t)la[1] << 16), (uint32_t)la[2] | ((uint32_t)la[3] << 16),
               (uint32_t)la[4] | ((uint32_t)la[5] << 16), (uint32_t)la[6] | ((uint32_t)la[7] << 16)};
  uint4 hvp = {(uint32_t)hp[0] | ((uint32_t)hp[1] << 16), (uint32_t)hp[2] | ((uint32_t)hp[3] << 16),
               (uint32_t)hp[4] | ((uint32_t)hp[5] << 16), (uint32_t)hp[6] | ((uint32_t)hp[7] << 16)};
  uint4 lvp = {(uint32_t)lp[0] | ((uint32_t)lp[1] << 16), (uint32_t)lp[2] | ((uint32_t)lp[3] << 16),
               (uint32_t)lp[4] | ((uint32_t)lp[5] << 16), (uint32_t)lp[6] | ((uint32_t)lp[7] << 16)};
  ((uint4*)(zhi + (size_t)i * DIM))[lane] = hva;
  ((uint4*)(zlo + (size_t)i * DIM))[lane] = lva;
  ((uint4*)(zhi + (size_t)(i + BHALF) * DIM))[lane] = hvp;
  ((uint4*)(zlo + (size_t)(i + BHALF) * DIM))[lane] = lvp;
  __syncthreads();
  if (threadIdx.x == 0) {
    atomicAdd(&scalars[0], tr_sh[0] + tr_sh[1] + tr_sh[2] + tr_sh[3]);
    atomicAdd(&scalars[1], pd_sh[0] + pd_sh[1] + pd_sh[2] + pd_sh[3]);
  }
}

// ---------------- main fused kernel: riders (colstats) + 128^2 4-slot pipelined GEMM ----------------
extern "C" __global__ __launch_bounds__(256, 1) void k_gemm(
    const unsigned short* __restrict__ wsbase,   // zhi at 0, zlo at NROWS*DIM elems
    const float* __restrict__ za, const float* __restrict__ zp,
    const float* __restrict__ inv_norms,
    float* __restrict__ sumexp, unsigned long long* __restrict__ amax,
    float* __restrict__ colsum, float* __restrict__ colsumsq,
    float* __restrict__ snorm)
{
  // 4 circular slots x 32KB; slot = [Ahi 8K][Alo 8K][Bhi 8K][Blo 8K], panel [128][32] bf16
  __shared__ char lds[4 * 32768] __attribute__((aligned(128)));

  // ---- rider blocks: column stats, overlapped with GEMM ----
  if (blockIdx.x < NRIDER) {
    const int c = threadIdx.x;          // 256 threads, 2 columns each
    const int r0 = blockIdx.x * 128;
    const float* src = (r0 < BHALF) ? (za + (size_t)r0 * DIM)
                                    : (zp + (size_t)(r0 - BHALF) * DIM);
    float s0 = 0.f, q0 = 0.f, n0 = 0.f, s1 = 0.f, q1 = 0.f, n1 = 0.f;
#pragma unroll 4
    for (int rr = 0; rr < 128; ++rr) {
      float v0 = src[(size_t)rr * DIM + c];
      float v1 = src[(size_t)rr * DIM + c + 256];
      float inv = inv_norms[r0 + rr];
      s0 += v0; q0 += v0 * v0; n0 += v0 * inv;
      s1 += v1; q1 += v1 * v1; n1 += v1 * inv;
    }
    atomicAdd(&colsum[c], s0);      atomicAdd(&colsum[c + 256], s1);
    atomicAdd(&colsumsq[c], q0);    atomicAdd(&colsumsq[c + 256], q1);
    atomicAdd(&snorm[c], n0);       atomicAdd(&snorm[c + 256], n1);
    return;
  }

  const int tid = threadIdx.x;
  const int wid = tid >> 6, lane = tid & 63;
  const int wr = wid >> 1, wc = wid & 1;
  const int fr = lane & 15, slot0 = lane >> 4, fq = lane >> 4;

  // XCD-chunked column-major triangle: XCD k gets t in [260k, 260(k+1))
  const int raw = blockIdx.x - NRIDER;               // 0..2079
  const int t = (raw & 7) * 260 + (raw >> 3);
  // column-major decode: t -> (bi, bj), bi <= bj  (t = bj(bj+1)/2 + bi)
  int bj = (int)((sqrtf(8.0f * (float)t + 1.0f) - 1.0f) * 0.5f);
  while (bj < NBLK - 1 && (bj + 1) * (bj + 2) / 2 <= t) ++bj;
  while (bj > 0 && bj * (bj + 1) / 2 > t) --bj;
  const int bi = t - bj * (bj + 1) / 2;
  const int rowA = bi * 128, rowB = bj * 128;

  // ---- per-lane global source offsets for this wave's 8 staging chunks (1KB each) ----
  // slot layout: chunk c = wid*8+s in [0,32); panel p=c>>3 (0=Ahi,1=Alo,2=Bhi,3=Blo)
  // physical byte in panel = logical ^ (((row>>1)&3)<<4)  (involution on bits 4:5)
  uint32_t goff[8];
#pragma unroll
  for (int s = 0; s < 8; ++s) {
    int c = wid * 8 + s;
    int p = c >> 3;
    int offp = (c & 7) * 1024 + lane * 16;   // physical byte within 8KB panel
    int r = offp >> 6;
    int L = offp ^ (((r >> 1) & 3) << 4);    // logical byte
    int cb = L & 63;
    uint32_t rowg = (uint32_t)(((p & 2) ? rowB : rowA) + r);
    uint32_t arr = (p & 1) ? (uint32_t)(NROWS * DIM) : 0u;   // zlo elem offset
    goff[s] = arr + rowg * (uint32_t)DIM + (uint32_t)(cb >> 1);
  }

  // ds_read base offsets (slot-relative, swizzled; swz-slot invariant across m*16)
  const int r0A = wr * 64 + fr;
  const int aoff = r0A * 64 + ((slot0 ^ ((r0A >> 1) & 3)) << 4);
  const int r0B = wc * 64 + fr;
  const int boff = r0B * 64 + ((slot0 ^ ((r0B >> 1) & 3)) << 4);

  f32x4 acc[4][4];
#pragma unroll
  for (int m = 0; m < 4; ++m)
#pragma unroll
    for (int n = 0; n < 4; ++n) acc[m][n] = (f32x4){0.f, 0.f, 0.f, 0.f};

  bf16x8 AH[2][4], AL[2][4], BH[2][4], BL[2][4];

#define READ_FRAGS(SET, SLOT) do {                                         \
    const char* sb_ = (const char*)lds + (SLOT) * 32768;                   \
    _Pragma("unroll") for (int m_ = 0; m_ < 4; ++m_) {                     \
      AH[SET][m_] = *(const bf16x8*)(sb_ +         aoff + m_ * 1024);      \
      AL[SET][m_] = *(const bf16x8*)(sb_ +  8192 + aoff + m_ * 1024);      \
    }                                                                      \
    _Pragma("unroll") for (int n_ = 0; n_ < 4; ++n_) {                     \
      BH[SET][n_] = *(const bf16x8*)(sb_ + 16384 + boff + n_ * 1024);      \
      BL[SET][n_] = *(const bf16x8*)(sb_ + 24576 + boff + n_ * 1024);      \
    }                                                                      \
  } while (0)

#define MFMA_SET(SET) do {                                                         \
    _Pragma("unroll") for (int m_ = 0; m_ < 4; ++m_)                               \
    _Pragma("unroll") for (int n_ = 0; n_ < 4; ++n_) {                             \
      acc[m_][n_] = __builtin_amdgcn_mfma_f32_16x16x32_bf16(AH[SET][m_], BH[SET][n_], acc[m_][n_], 0, 0, 0); \
      acc[m_][n_] = __builtin_amdgcn_mfma_f32_16x16x32_bf16(AH[SET][m_], BL[SET][n_], acc[m_][n_], 0, 0, 0); \
      acc[m_][n_] = __builtin_amdgcn_mfma_f32_16x16x32_bf16(AL[SET][m_], BH[SET][n_], acc[m_][n_], 0, 0, 0); \
    }                                                                              \
  } while (0)

  // ---- prologue: issue K-steps 0,1,2 into slots 0,1,2 (24 loads/wave in flight) ----
#pragma unroll
  for (int st = 0; st < 3; ++st) {
    char* D = (char*)lds + st * 32768 + wid * 8192;
#pragma unroll
    for (int s = 0; s < 8; ++s)
      gload_lds16(wsbase + goff[s] + st * 32, D + s * 1024);
  }
  asm volatile("s_waitcnt vmcnt(16)" ::: "memory");   // slot 0 landed (own)
  __builtin_amdgcn_s_barrier();                       // all waves' slot-0 landed
  __builtin_amdgcn_sched_barrier(0);
  READ_FRAGS(0, 0);
  asm volatile("s_waitcnt lgkmcnt(0)" ::: "memory");
  __builtin_amdgcn_sched_barrier(0);

  // ---- main loop: per kt: wait slot kt+1, issue slot kt+3, read(kt+1) || MFMA(kt) ----
#pragma unroll
  for (int kt = 0; kt < 15; ++kt) {
    if (kt <= 13) asm volatile("s_waitcnt vmcnt(8)" ::: "memory");  // slot kt+1 landed
    else          asm volatile("s_waitcnt vmcnt(0)" ::: "memory");  // kt=14: slot 15
    __builtin_amdgcn_s_barrier();
    __builtin_amdgcn_sched_barrier(0);
    if (kt <= 12) {            // issue K-step kt+3 into slot (kt+3)&3 (= slot (kt-1)&3, now free)
      char* D = (char*)lds + ((kt + 3) & 3) * 32768 + wid * 8192;
#pragma unroll
      for (int s = 0; s < 8; ++s)
        gload_lds16(wsbase + goff[s] + (kt + 3) * 32, D + s * 1024);
    }
    READ_FRAGS((kt + 1) & 1, (kt + 1) & 3);
    __builtin_amdgcn_s_setprio(1);
    MFMA_SET(kt & 1);
    __builtin_amdgcn_s_setprio(0);
    asm volatile("s_waitcnt lgkmcnt(0)" ::: "memory");
    __builtin_amdgcn_sched_barrier(0);
  }
  MFMA_SET(1);   // kt = 15

  // ---- epilogue ----
  // row-side: rows gi in A-panel, reduce across 16 col-lanes (fr) + n
#pragma unroll
  for (int m = 0; m < 4; ++m) {
#pragma unroll
    for (int rr = 0; rr < 4; ++rr) {
      int gi = rowA + wr * 64 + m * 16 + fq * 4 + rr;
      float se = 0.f;
      unsigned long long best = 0ull;
#pragma unroll
      for (int n = 0; n < 4; ++n) {
        int gj = rowB + wc * 64 + n * 16 + fr;
        if (gi != gj) {
          float logit = 2.0f * acc[m][n][rr];   // /T with T=0.5
          se += __expf(logit);
          uint32_t bu = __float_as_uint(logit);
          uint32_t sk = (bu & 0x80000000u) ? ~bu : (bu | 0x80000000u);
          unsigned long long pk =
              ((unsigned long long)sk << 32) | (uint32_t)(~(uint32_t)gj);
          if (pk > best) best = pk;
        }
      }
#pragma unroll
      for (int msk = 1; msk < 16; msk <<= 1) {
        se += __shfl_xor(se, msk, 64);
        unsigned long long o = __shfl_xor(best, msk, 64);
        if (o > best) best = o;
      }
      if (fr == 0) {
        atomicAdd(&sumexp[gi], se);
        atomicMax(&amax[gi], best);
      }
    }
  }

  // col-side (off-diagonal only): rows gj in B-panel via cos^T = cos
  if (bi != bj) {
#pragma unroll
    for (int n = 0; n < 4; ++n) {
      int gj = rowB + wc * 64 + n * 16 + fr;
      float se = 0.f;
      unsigned long long best = 0ull;
#pragma unroll
      for (int m = 0; m < 4; ++m) {
#pragma unroll
        for (int rr = 0; rr < 4; ++rr) {
          int gi = rowA + wr * 64 + m * 16 + fq * 4 + rr;
          float logit = 2.0f * acc[m][n][rr];
          se += __expf(logit);
          uint32_t bu = __float_as_uint(logit);
          uint32_t sk = (bu & 0x80000000u) ? ~bu : (bu | 0x80000000u);
          unsigned long long pk =
              ((unsigned long long)sk << 32) | (uint32_t)(~(uint32_t)gi);
          if (pk > best) best = pk;
        }
      }
#pragma unroll
      for (int msk = 16; msk < 64; msk <<= 1) {
        se += __shfl_xor(se, msk, 64);
        unsigned long long o = __shfl_xor(best, msk, 64);
        if (o > best) best = o;
      }
      if (fq == 0) {
        atomicAdd(&sumexp[gj], se);
        atomicMax(&amax[gj], best);
      }
    }
  }
#undef READ_FRAGS
#undef MFMA_SET
}

// ---------------- final combine ----------------
extern "C" __global__ __launch_bounds__(1024) void k_final(
    const float* __restrict__ sumexp, const unsigned long long* __restrict__ amax,
    const float* __restrict__ colsum, const float* __restrict__ colsumsq,
    const float* __restrict__ snorm, const float* __restrict__ scalars,
    float* __restrict__ out)
{
  __shared__ double red[1024];
  const int t = threadIdx.x;
  double lsesum = 0.0, cnt = 0.0;
  for (int r = t; r < NROWS; r += 1024) {
    lsesum += log((double)sumexp[r]);
    int label = (r < BHALF) ? r + BHALF : r - BHALF;
    unsigned int idx = ~(unsigned int)(amax[r] & 0xffffffffull);
    if ((int)idx == label) cnt += 1.0;
  }
  double stdsum = 0, mn2 = 0, sn2 = 0;
  for (int c = t; c < DIM; c += 1024) {
    double su = colsum[c], sq = colsumsq[c];
    double var = (sq - su * su / 8192.0) / 8191.0;
    stdsum += sqrt(var > 0.0 ? var : 0.0);
    double m = su / 8192.0; mn2 += m * m;
    double s = snorm[c];   sn2 += s * s;
  }
  auto red_sum = [&](double v) -> double {
    __syncthreads();
    red[t] = v; __syncthreads();
    for (int s = 512; s > 0; s >>= 1) {
      if (t < s) red[t] += red[t + s];
      __syncthreads();
    }
    return red[0];
  };
  double Tlse = red_sum(lsesum);
  double Tcnt = red_sum(cnt);
  double Tstd = red_sum(stdsum);
  double Tmn2 = red_sum(mn2);
  double Tsn2 = red_sum(sn2);
  if (t == 0) {
    double trace = scalars[0], posdot = scalars[1];
    double pos_sim = posdot / 4096.0;
    out[0] = (float)(Tlse / 8192.0 - 2.0 * pos_sim);
    out[1] = (float)(Tcnt / 8192.0);
    out[2] = (float)pos_sim;
    out[3] = (float)((Tsn2 - trace) / (8192.0 * 8191.0));
    out[4] = (float)(Tstd / 512.0);
    out[5] = (float)sqrt(Tmn2);
  }
}

extern "C" void kernel_launch(void* const* d_in, const int* in_sizes, int n_in,
                              void* d_out, int out_size, void* d_ws, size_t ws_size,
                              hipStream_t stream) {
  const float* za = (const float*)d_in[0];
  const float* zp = (const float*)d_in[1];
  float* out = (float*)d_out;
  char* ws = (char*)d_ws;
  size_t off = 0;
  unsigned short* zhi = (unsigned short*)(ws + off); off += (size_t)NROWS * DIM * 2;
  unsigned short* zlo = (unsigned short*)(ws + off); off += (size_t)NROWS * DIM * 2;
  float* inv_norms = (float*)(ws + off); off += (size_t)NROWS * 4;
  char* zbase = ws + off;
  float* sumexp = (float*)(ws + off); off += (size_t)NROWS * 4;
  unsigned long long* amax = (unsigned long long*)(ws + off); off += (size_t)NROWS * 8;
  float* colsum = (float*)(ws + off); off += (size_t)DIM * 4;
  float* colsumsq = (float*)(ws + off); off += (size_t)DIM * 4;
  float* snorm = (float*)(ws + off); off += (size_t)DIM * 4;
  float* scalars = (float*)(ws + off); off += 64;
  size_t zsize = (size_t)((ws + off) - zbase);

  hipMemsetAsync(zbase, 0, zsize, stream);
  k_prep<<<dim3(1024), dim3(256), 0, stream>>>(za, zp, zhi, zlo, inv_norms, scalars);
  k_gemm<<<dim3(NTRI + NRIDER), dim3(256), 0, stream>>>(
      (const unsigned short*)ws, za, zp, inv_norms, sumexp, amax,
      colsum, colsumsq, snorm);
  k_final<<<dim3(1), dim3(1024), 0, stream>>>(sumexp, amax, colsum, colsumsq, snorm, scalars, out);
}

// Round 5
// 234.242 us; speedup vs baseline: 1.2656x; 1.2215x over previous
//
#include <hip/hip_runtime.h>
#include <stdint.h>

#define NROWS 8192
#define BHALF 4096
#define DIM 512
#define NB2 32             // 8192/256 row-blocks
#define NTRI2 528          // 32*33/2 upper-triangle blocks (= 8 XCDs * 66)
#define NRIDER 64          // colstats rider blocks (at grid tail)
#define ZWORDS 26112       // sumexp 8192 + amax 16384 + col* 1536 (u32 words)

typedef __attribute__((ext_vector_type(8))) short bf16x8;
typedef __attribute__((ext_vector_type(4))) float f32x4;

__device__ __forceinline__ unsigned short f32_to_bf16(float f) {
  uint32_t u = __float_as_uint(f);
  u += 0x7fffu + ((u >> 16) & 1u);
  return (unsigned short)(u >> 16);
}
__device__ __forceinline__ float bf16_to_f32(unsigned short h) {
  return __uint_as_float(((uint32_t)h) << 16);
}

__device__ __forceinline__ void gload_lds16(const void* g, void* l) {
  __builtin_amdgcn_global_load_lds(
      (const __attribute__((address_space(1))) unsigned int*)g,
      (__attribute__((address_space(3))) unsigned int*)l, 16, 0, 0);
}

// ---------------- fused prep: norms, bf16 hi/lo split, partials, zero-init ----------------
extern "C" __global__ __launch_bounds__(256) void k_prep(
    const float* __restrict__ za, const float* __restrict__ zp,
    unsigned short* __restrict__ zhi, unsigned short* __restrict__ zlo,
    float* __restrict__ inv_norms, float* __restrict__ partials,
    uint32_t* __restrict__ zbase32)
{
  // zero the accumulator region (consumed by k_gemm, a later dispatch -> safe)
  {
    int idx = blockIdx.x * 26 + threadIdx.x;
    if (threadIdx.x < 26 && idx < ZWORDS) zbase32[idx] = 0u;
  }
  __shared__ float tr_sh[4], pd_sh[4];
  const int wid = threadIdx.x >> 6, lane = threadIdx.x & 63;
  const int i = blockIdx.x * 4 + wid;                 // pair index in [0,4096)
  const float4* a4 = (const float4*)(za + (size_t)i * DIM);
  const float4* p4 = (const float4*)(zp + (size_t)i * DIM);
  float4 a0 = a4[lane * 2], a1 = a4[lane * 2 + 1];
  float4 p0 = p4[lane * 2], p1 = p4[lane * 2 + 1];
  float xa[8] = {a0.x, a0.y, a0.z, a0.w, a1.x, a1.y, a1.z, a1.w};
  float xp[8] = {p0.x, p0.y, p0.z, p0.w, p1.x, p1.y, p1.z, p1.w};
  float ssa = 0.f, ssp = 0.f;
#pragma unroll
  for (int j = 0; j < 8; ++j) { ssa += xa[j] * xa[j]; ssp += xp[j] * xp[j]; }
#pragma unroll
  for (int m = 1; m < 64; m <<= 1) {
    ssa += __shfl_xor(ssa, m, 64);
    ssp += __shfl_xor(ssp, m, 64);
  }
  float na = fmaxf(sqrtf(ssa), 1e-8f), np_ = fmaxf(sqrtf(ssp), 1e-8f);
  float ia = 1.0f / na, ip = 1.0f / np_;
  float pd = 0.f;
  unsigned short ha[8], la[8], hp[8], lp[8];
#pragma unroll
  for (int j = 0; j < 8; ++j) {
    float zna = xa[j] * ia, znp = xp[j] * ip;
    pd += zna * znp;
    ha[j] = f32_to_bf16(zna); la[j] = f32_to_bf16(zna - bf16_to_f32(ha[j]));
    hp[j] = f32_to_bf16(znp); lp[j] = f32_to_bf16(znp - bf16_to_f32(hp[j]));
  }
#pragma unroll
  for (int m = 1; m < 64; m <<= 1) pd += __shfl_xor(pd, m, 64);
  float tr = ssa * ia * ia + ssp * ip * ip;
  if (lane == 0) {
    tr_sh[wid] = tr; pd_sh[wid] = pd;
    inv_norms[i] = ia; inv_norms[i + BHALF] = ip;
  }
  uint4 hva = {(uint32_t)ha[0] | ((uint32_t)ha[1] << 16), (uint32_t)ha[2] | ((uint32_t)ha[3] << 16),
               (uint32_t)ha[4] | ((uint32_t)ha[5] << 16), (uint32_t)ha[6] | ((uint32_t)ha[7] << 16)};
  uint4 lva = {(uint32_t)la[0] | ((uint32_t)la[1] << 16), (uint32_t)la[2] | ((uint32_t)la[3] << 16),
               (uint32_t)la[4] | ((uint32_t)la[5] << 16), (uint32_t)la[6] | ((uint32_t)la[7] << 16)};
  uint4 hvp = {(uint32_t)hp[0] | ((uint32_t)hp[1] << 16), (uint32_t)hp[2] | ((uint32_t)hp[3] << 16),
               (uint32_t)hp[4] | ((uint32_t)hp[5] << 16), (uint32_t)hp[6] | ((uint32_t)hp[7] << 16)};
  uint4 lvp = {(uint32_t)lp[0] | ((uint32_t)lp[1] << 16), (uint32_t)lp[2] | ((uint32_t)lp[3] << 16),
               (uint32_t)lp[4] | ((uint32_t)lp[5] << 16), (uint32_t)lp[6] | ((uint32_t)lp[7] << 16)};
  ((uint4*)(zhi + (size_t)i * DIM))[lane] = hva;
  ((uint4*)(zlo + (size_t)i * DIM))[lane] = lva;
  ((uint4*)(zhi + (size_t)(i + BHALF) * DIM))[lane] = hvp;
  ((uint4*)(zlo + (size_t)(i + BHALF) * DIM))[lane] = lvp;
  __syncthreads();
  if (threadIdx.x == 0) {
    partials[blockIdx.x * 2]     = tr_sh[0] + tr_sh[1] + tr_sh[2] + tr_sh[3];
    partials[blockIdx.x * 2 + 1] = pd_sh[0] + pd_sh[1] + pd_sh[2] + pd_sh[3];
  }
}

// ---------------- main fused kernel: 256^2 8-wave 4-phase GEMM + rider colstats ----------------
extern "C" __global__ __launch_bounds__(512, 2) void k_gemm(
    const unsigned short* __restrict__ wsbase,   // zhi at 0, zlo at NROWS*DIM elems
    const float* __restrict__ za, const float* __restrict__ zp,
    const float* __restrict__ inv_norms,
    float* __restrict__ sumexp, unsigned long long* __restrict__ amax,
    float* __restrict__ colsum, float* __restrict__ colsumsq,
    float* __restrict__ snorm)
{
  // double buffer: 2 slots x 64KB; slot = [Ahi 16K][Alo 16K][Bhi 16K][Blo 16K], panel [256][32] bf16
  __shared__ char lds[2 * 65536] __attribute__((aligned(128)));

  // ---- rider blocks at grid tail: column stats ----
  if (blockIdx.x >= NTRI2) {
    const int c = threadIdx.x;          // 512 threads = 512 columns
    const int r0 = (blockIdx.x - NTRI2) * 128;
    const float* src = (r0 < BHALF) ? (za + (size_t)r0 * DIM)
                                    : (zp + (size_t)(r0 - BHALF) * DIM);
    float s = 0.f, q = 0.f, nm = 0.f;
#pragma unroll 4
    for (int rr = 0; rr < 128; ++rr) {
      float v = src[(size_t)rr * DIM + c];
      float inv = inv_norms[r0 + rr];
      s += v; q += v * v; nm += v * inv;
    }
    atomicAdd(&colsum[c], s);
    atomicAdd(&colsumsq[c], q);
    atomicAdd(&snorm[c], nm);
    return;
  }

  const int tid = threadIdx.x;
  const int w = tid >> 6, lane = tid & 63;
  const int wr = w >> 2, wc = w & 3;                 // 2x4 wave grid
  const int fr = lane & 15, slot0 = lane >> 4, fq = lane >> 4;

  // XCD-chunked column-major triangle: XCD k (= blockIdx%8) gets 66 consecutive t
  const int raw = blockIdx.x;                        // 0..527
  const int t = (raw & 7) * 66 + (raw >> 3);
  // column-major decode: t = bj(bj+1)/2 + bi, bi <= bj
  int bj = (int)((sqrtf(8.0f * (float)t + 1.0f) - 1.0f) * 0.5f);
  while (bj < NB2 - 1 && (bj + 1) * (bj + 2) / 2 <= t) ++bj;
  while (bj > 0 && bj * (bj + 1) / 2 > t) --bj;
  const int bi = t - bj * (bj + 1) / 2;
  const int rowA = bi * 256, rowB = bj * 256;

  // ---- per-lane global source offsets for this wave's 8 staging chunks (1KB each) ----
  // chunk c = w*8+s in [0,64); panel p=c>>4 (0=Ahi,1=Alo,2=Bhi,3=Blo), 16 chunks/panel
  // physical byte in panel = logical ^ (((row>>1)&3)<<4)  (involution on bits 4:5)
  uint32_t goff[8];
#pragma unroll
  for (int s = 0; s < 8; ++s) {
    int c = w * 8 + s;
    int p = c >> 4;
    int offp = (c & 15) * 1024 + lane * 16;   // physical byte within 16KB panel
    int r = offp >> 6;
    int L = offp ^ (((r >> 1) & 3) << 4);     // logical byte
    int cb = L & 63;
    uint32_t rowg = (uint32_t)(((p & 2) ? rowB : rowA) + r);
    uint32_t arr = (p & 1) ? (uint32_t)(NROWS * DIM) : 0u;   // zlo elem offset
    goff[s] = arr + rowg * (uint32_t)DIM + (uint32_t)(cb >> 1);
  }

  // ds_read base offsets (slot-panel-relative, swizzled; invariant across +16-row steps)
  const int r0A = wr * 128 + fr;
  const int aoff = r0A * 64 + ((slot0 ^ ((r0A >> 1) & 3)) << 4);
  const int r0B = wc * 64 + fr;
  const int boff = r0B * 64 + ((slot0 ^ ((r0B >> 1) & 3)) << 4);

  f32x4 acc[8][4];
#pragma unroll
  for (int m = 0; m < 8; ++m)
#pragma unroll
    for (int n = 0; n < 4; ++n) acc[m][n] = (f32x4){0.f, 0.f, 0.f, 0.f};

#define TERM3(MI, XH, XL)                                                              \
  _Pragma("unroll") for (int n_ = 0; n_ < 4; ++n_) {                                   \
    acc[MI][n_] = __builtin_amdgcn_mfma_f32_16x16x32_bf16(XH, bh[n_], acc[MI][n_], 0, 0, 0); \
    acc[MI][n_] = __builtin_amdgcn_mfma_f32_16x16x32_bf16(XH, bl[n_], acc[MI][n_], 0, 0, 0); \
    acc[MI][n_] = __builtin_amdgcn_mfma_f32_16x16x32_bf16(XL, bh[n_], acc[MI][n_], 0, 0, 0); \
  }

  // ---- prologue: stage K-step 0 into slot 0 ----
  {
    char* D = (char*)lds + w * 8192;
#pragma unroll
    for (int s = 0; s < 8; ++s)
      gload_lds16(wsbase + goff[s], D + s * 1024);
  }

  // ---- main loop: per kt, 1 vmcnt+barrier, 4 MFMA phases, prefetch spread ----
#pragma unroll 2
  for (int kt = 0; kt < 16; ++kt) {
    asm volatile("s_waitcnt vmcnt(0)" ::: "memory");   // slot kt&1 landed (own 8)
    __builtin_amdgcn_s_barrier();                      // all waves landed + old reads done
    __builtin_amdgcn_sched_barrier(0);
    const char* Lb = (const char*)lds + (kt & 1) * 65536;
    char* Db = (char*)lds + ((kt & 1) ^ 1) * 65536 + w * 8192;
    const uint32_t ko = (uint32_t)(kt + 1) * 32;
    if (kt < 15) {                                     // prefetch chunks 0-3
#pragma unroll
      for (int s = 0; s < 4; ++s)
        gload_lds16(wsbase + goff[s] + ko, Db + s * 1024);
    }
    // B fragments (resident for the whole kt)
    bf16x8 bh[4], bl[4];
#pragma unroll
    for (int n_ = 0; n_ < 4; ++n_) {
      bh[n_] = *(const bf16x8*)(Lb + 32768 + boff + n_ * 1024);
      bl[n_] = *(const bf16x8*)(Lb + 49152 + boff + n_ * 1024);
    }
    // phase 0: m0,m1
    {
      bf16x8 xh0 = *(const bf16x8*)(Lb + aoff + 0 * 1024);
      bf16x8 xh1 = *(const bf16x8*)(Lb + aoff + 1 * 1024);
      bf16x8 xl0 = *(const bf16x8*)(Lb + 16384 + aoff + 0 * 1024);
      bf16x8 xl1 = *(const bf16x8*)(Lb + 16384 + aoff + 1 * 1024);
      __builtin_amdgcn_s_setprio(1);
      TERM3(0, xh0, xl0)
      TERM3(1, xh1, xl1)
      __builtin_amdgcn_s_setprio(0);
    }
    // phase 1: m2,m3
    {
      bf16x8 xh0 = *(const bf16x8*)(Lb + aoff + 2 * 1024);
      bf16x8 xh1 = *(const bf16x8*)(Lb + aoff + 3 * 1024);
      bf16x8 xl0 = *(const bf16x8*)(Lb + 16384 + aoff + 2 * 1024);
      bf16x8 xl1 = *(const bf16x8*)(Lb + 16384 + aoff + 3 * 1024);
      __builtin_amdgcn_s_setprio(1);
      TERM3(2, xh0, xl0)
      TERM3(3, xh1, xl1)
      __builtin_amdgcn_s_setprio(0);
    }
    // phase 2: prefetch chunks 4-7; m4,m5
    if (kt < 15) {
#pragma unroll
      for (int s = 4; s < 8; ++s)
        gload_lds16(wsbase + goff[s] + ko, Db + s * 1024);
    }
    {
      bf16x8 xh0 = *(const bf16x8*)(Lb + aoff + 4 * 1024);
      bf16x8 xh1 = *(const bf16x8*)(Lb + aoff + 5 * 1024);
      bf16x8 xl0 = *(const bf16x8*)(Lb + 16384 + aoff + 4 * 1024);
      bf16x8 xl1 = *(const bf16x8*)(Lb + 16384 + aoff + 5 * 1024);
      __builtin_amdgcn_s_setprio(1);
      TERM3(4, xh0, xl0)
      TERM3(5, xh1, xl1)
      __builtin_amdgcn_s_setprio(0);
    }
    // phase 3: m6,m7
    {
      bf16x8 xh0 = *(const bf16x8*)(Lb + aoff + 6 * 1024);
      bf16x8 xh1 = *(const bf16x8*)(Lb + aoff + 7 * 1024);
      bf16x8 xl0 = *(const bf16x8*)(Lb + 16384 + aoff + 6 * 1024);
      bf16x8 xl1 = *(const bf16x8*)(Lb + 16384 + aoff + 7 * 1024);
      __builtin_amdgcn_s_setprio(1);
      TERM3(6, xh0, xl0)
      TERM3(7, xh1, xl1)
      __builtin_amdgcn_s_setprio(0);
    }
  }
#undef TERM3

  // ---- epilogue (verified r3 mapping) ----
  // row-side: rows gi in A-panel (wave's 128-row half), reduce over fr lanes + n
#pragma unroll
  for (int m = 0; m < 8; ++m) {
#pragma unroll
    for (int rr = 0; rr < 4; ++rr) {
      int gi = rowA + wr * 128 + m * 16 + fq * 4 + rr;
      float se = 0.f;
      unsigned long long best = 0ull;
#pragma unroll
      for (int n = 0; n < 4; ++n) {
        int gj = rowB + wc * 64 + n * 16 + fr;
        if (gi != gj) {
          float logit = 2.0f * acc[m][n][rr];   // /T with T=0.5
          se += __expf(logit);
          uint32_t bu = __float_as_uint(logit);
          uint32_t sk = (bu & 0x80000000u) ? ~bu : (bu | 0x80000000u);
          unsigned long long pk =
              ((unsigned long long)sk << 32) | (uint32_t)(~(uint32_t)gj);
          if (pk > best) best = pk;
        }
      }
#pragma unroll
      for (int msk = 1; msk < 16; msk <<= 1) {
        se += __shfl_xor(se, msk, 64);
        unsigned long long o = __shfl_xor(best, msk, 64);
        if (o > best) best = o;
      }
      if (fr == 0) {
        atomicAdd(&sumexp[gi], se);
        atomicMax(&amax[gi], best);
      }
    }
  }

  // col-side (off-diagonal only): rows gj in B-panel via cos^T = cos
  if (bi != bj) {
#pragma unroll
    for (int n = 0; n < 4; ++n) {
      int gj = rowB + wc * 64 + n * 16 + fr;
      float se = 0.f;
      unsigned long long best = 0ull;
#pragma unroll
      for (int m = 0; m < 8; ++m) {
#pragma unroll
        for (int rr = 0; rr < 4; ++rr) {
          int gi = rowA + wr * 128 + m * 16 + fq * 4 + rr;
          float logit = 2.0f * acc[m][n][rr];
          se += __expf(logit);
          uint32_t bu = __float_as_uint(logit);
          uint32_t sk = (bu & 0x80000000u) ? ~bu : (bu | 0x80000000u);
          unsigned long long pk =
              ((unsigned long long)sk << 32) | (uint32_t)(~(uint32_t)gi);
          if (pk > best) best = pk;
        }
      }
#pragma unroll
      for (int msk = 16; msk < 64; msk <<= 1) {
        se += __shfl_xor(se, msk, 64);
        unsigned long long o = __shfl_xor(best, msk, 64);
        if (o > best) best = o;
      }
      if (fq == 0) {
        atomicAdd(&sumexp[gj], se);
        atomicMax(&amax[gj], best);
      }
    }
  }
}

// ---------------- final combine ----------------
extern "C" __global__ __launch_bounds__(1024) void k_final(
    const float* __restrict__ sumexp, const unsigned long long* __restrict__ amax,
    const float* __restrict__ colsum, const float* __restrict__ colsumsq,
    const float* __restrict__ snorm, const float* __restrict__ partials,
    float* __restrict__ out)
{
  __shared__ double red[1024];
  const int t = threadIdx.x;
  double lsesum = 0.0, cnt = 0.0;
  for (int r = t; r < NROWS; r += 1024) {
    lsesum += log((double)sumexp[r]);
    int label = (r < BHALF) ? r + BHALF : r - BHALF;
    unsigned int idx = ~(unsigned int)(amax[r] & 0xffffffffull);
    if ((int)idx == label) cnt += 1.0;
  }
  double stdsum = 0, mn2 = 0, sn2 = 0;
  for (int c = t; c < DIM; c += 1024) {
    double su = colsum[c], sq = colsumsq[c];
    double var = (sq - su * su / 8192.0) / 8191.0;
    stdsum += sqrt(var > 0.0 ? var : 0.0);
    double m = su / 8192.0; mn2 += m * m;
    double s = snorm[c];   sn2 += s * s;
  }
  double trp = 0.0, pdp = 0.0;
  for (int b = t; b < 1024; b += 1024) {   // t < 1024 -> one element each
    trp += partials[b * 2];
    pdp += partials[b * 2 + 1];
  }
  auto red_sum = [&](double v) -> double {
    __syncthreads();
    red[t] = v; __syncthreads();
    for (int s = 512; s > 0; s >>= 1) {
      if (t < s) red[t] += red[t + s];
      __syncthreads();
    }
    return red[0];
  };
  double Tlse = red_sum(lsesum);
  double Tcnt = red_sum(cnt);
  double Tstd = red_sum(stdsum);
  double Tmn2 = red_sum(mn2);
  double Tsn2 = red_sum(sn2);
  double Ttr  = red_sum(trp);
  double Tpd  = red_sum(pdp);
  if (t == 0) {
    double pos_sim = Tpd / 4096.0;
    out[0] = (float)(Tlse / 8192.0 - 2.0 * pos_sim);
    out[1] = (float)(Tcnt / 8192.0);
    out[2] = (float)pos_sim;
    out[3] = (float)((Tsn2 - Ttr) / (8192.0 * 8191.0));
    out[4] = (float)(Tstd / 512.0);
    out[5] = (float)sqrt(Tmn2);
  }
}

extern "C" void kernel_launch(void* const* d_in, const int* in_sizes, int n_in,
                              void* d_out, int out_size, void* d_ws, size_t ws_size,
                              hipStream_t stream) {
  const float* za = (const float*)d_in[0];
  const float* zp = (const float*)d_in[1];
  float* out = (float*)d_out;
  char* ws = (char*)d_ws;
  size_t off = 0;
  unsigned short* zhi = (unsigned short*)(ws + off); off += (size_t)NROWS * DIM * 2;
  unsigned short* zlo = (unsigned short*)(ws + off); off += (size_t)NROWS * DIM * 2;
  float* inv_norms = (float*)(ws + off); off += (size_t)NROWS * 4;
  char* zbase = ws + off;                              // zero-init'd by k_prep
  float* sumexp = (float*)(ws + off); off += (size_t)NROWS * 4;
  unsigned long long* amax = (unsigned long long*)(ws + off); off += (size_t)NROWS * 8;
  float* colsum = (float*)(ws + off); off += (size_t)DIM * 4;
  float* colsumsq = (float*)(ws + off); off += (size_t)DIM * 4;
  float* snorm = (float*)(ws + off); off += (size_t)DIM * 4;
  float* partials = (float*)(ws + off); off += 2048 * 4;

  k_prep<<<dim3(1024), dim3(256), 0, stream>>>(za, zp, zhi, zlo, inv_norms,
                                               partials, (uint32_t*)zbase);
  k_gemm<<<dim3(NTRI2 + NRIDER), dim3(512), 0, stream>>>(
      (const unsigned short*)ws, za, zp, inv_norms, sumexp, amax,
      colsum, colsumsq, snorm);
  k_final<<<dim3(1), dim3(1024), 0, stream>>>(sumexp, amax, colsum, colsumsq,
                                              snorm, partials, out);
}

// Round 6
// 151.175 us; speedup vs baseline: 1.9611x; 1.5495x over previous
//
#include <hip/hip_runtime.h>
#include <stdint.h>

#define NROWS 8192
#define BHALF 4096
#define DIM 512
#define NBLK 64            // 8192/128 row-blocks
#define NTRI 2080          // 64*65/2 upper-triangle blocks (= 8 XCDs * 260)
#define NRIDER 64          // colstats rider blocks (blockIdx < 64)
#define ZWORDS 26112       // sumexp 8192 + amax 16384 + col* 1536 (u32 words)

typedef __attribute__((ext_vector_type(8))) _Float16 f16x8;
typedef __attribute__((ext_vector_type(4))) float f32x4;

__device__ __forceinline__ void gload_lds16(const void* g, void* l) {
  __builtin_amdgcn_global_load_lds(
      (const __attribute__((address_space(1))) unsigned int*)g,
      (__attribute__((address_space(3))) unsigned int*)l, 16, 0, 0);
}

// ---------------- fused prep: norms, fp16 convert, partials, zero-init ----------------
extern "C" __global__ __launch_bounds__(256) void k_prep(
    const float* __restrict__ za, const float* __restrict__ zp,
    unsigned short* __restrict__ zf,
    float* __restrict__ inv_norms, float* __restrict__ partials,
    uint32_t* __restrict__ zbase32)
{
  // zero the accumulator region (consumed only by k_gemm, a later dispatch)
  {
    int idx = blockIdx.x * 26 + threadIdx.x;
    if (threadIdx.x < 26 && idx < ZWORDS) zbase32[idx] = 0u;
  }
  __shared__ float tr_sh[4], pd_sh[4];
  const int wid = threadIdx.x >> 6, lane = threadIdx.x & 63;
  const int i = blockIdx.x * 4 + wid;                 // pair index in [0,4096)
  const float4* a4 = (const float4*)(za + (size_t)i * DIM);
  const float4* p4 = (const float4*)(zp + (size_t)i * DIM);
  float4 a0 = a4[lane * 2], a1 = a4[lane * 2 + 1];
  float4 p0 = p4[lane * 2], p1 = p4[lane * 2 + 1];
  float xa[8] = {a0.x, a0.y, a0.z, a0.w, a1.x, a1.y, a1.z, a1.w};
  float xp[8] = {p0.x, p0.y, p0.z, p0.w, p1.x, p1.y, p1.z, p1.w};
  float ssa = 0.f, ssp = 0.f;
#pragma unroll
  for (int j = 0; j < 8; ++j) { ssa += xa[j] * xa[j]; ssp += xp[j] * xp[j]; }
#pragma unroll
  for (int m = 1; m < 64; m <<= 1) {
    ssa += __shfl_xor(ssa, m, 64);
    ssp += __shfl_xor(ssp, m, 64);
  }
  float na = fmaxf(sqrtf(ssa), 1e-8f), np_ = fmaxf(sqrtf(ssp), 1e-8f);
  float ia = 1.0f / na, ip = 1.0f / np_;
  float pd = 0.f;
  unsigned short ua[8], up[8];
#pragma unroll
  for (int j = 0; j < 8; ++j) {
    float zna = xa[j] * ia, znp = xp[j] * ip;
    pd += zna * znp;
    _Float16 hza = (_Float16)zna, hzp = (_Float16)znp;   // RNE
    ua[j] = __builtin_bit_cast(unsigned short, hza);
    up[j] = __builtin_bit_cast(unsigned short, hzp);
  }
#pragma unroll
  for (int m = 1; m < 64; m <<= 1) pd += __shfl_xor(pd, m, 64);
  float tr = ssa * ia * ia + ssp * ip * ip;
  if (lane == 0) {
    tr_sh[wid] = tr; pd_sh[wid] = pd;
    inv_norms[i] = ia; inv_norms[i + BHALF] = ip;
  }
  uint4 va = {(uint32_t)ua[0] | ((uint32_t)ua[1] << 16), (uint32_t)ua[2] | ((uint32_t)ua[3] << 16),
              (uint32_t)ua[4] | ((uint32_t)ua[5] << 16), (uint32_t)ua[6] | ((uint32_t)ua[7] << 16)};
  uint4 vp = {(uint32_t)up[0] | ((uint32_t)up[1] << 16), (uint32_t)up[2] | ((uint32_t)up[3] << 16),
              (uint32_t)up[4] | ((uint32_t)up[5] << 16), (uint32_t)up[6] | ((uint32_t)up[7] << 16)};
  ((uint4*)(zf + (size_t)i * DIM))[lane] = va;
  ((uint4*)(zf + (size_t)(i + BHALF) * DIM))[lane] = vp;
  __syncthreads();
  if (threadIdx.x == 0) {
    partials[blockIdx.x * 2]     = tr_sh[0] + tr_sh[1] + tr_sh[2] + tr_sh[3];
    partials[blockIdx.x * 2 + 1] = pd_sh[0] + pd_sh[1] + pd_sh[2] + pd_sh[3];
  }
}

// ---------------- main fused kernel: riders (colstats) + 128^2 fp16 GEMM ----------------
extern "C" __global__ __launch_bounds__(256) void k_gemm(
    const unsigned short* __restrict__ zf,
    const float* __restrict__ za, const float* __restrict__ zp,
    const float* __restrict__ inv_norms,
    float* __restrict__ sumexp, unsigned long long* __restrict__ amax,
    float* __restrict__ colsum, float* __restrict__ colsumsq,
    float* __restrict__ snorm)
{
  // [A 16K][B 16K]; each panel [128][64] fp16 (128 B rows), slot-XOR swizzled
  __shared__ char lds[32768] __attribute__((aligned(128)));

  // ---- rider blocks: column stats, overlapped with GEMM ----
  if (blockIdx.x < NRIDER) {
    const int c = threadIdx.x;          // 256 threads, 2 columns each
    const int r0 = blockIdx.x * 128;
    const float* src = (r0 < BHALF) ? (za + (size_t)r0 * DIM)
                                    : (zp + (size_t)(r0 - BHALF) * DIM);
    float s0 = 0.f, q0 = 0.f, n0 = 0.f, s1 = 0.f, q1 = 0.f, n1 = 0.f;
#pragma unroll 4
    for (int rr = 0; rr < 128; ++rr) {
      float v0 = src[(size_t)rr * DIM + c];
      float v1 = src[(size_t)rr * DIM + c + 256];
      float inv = inv_norms[r0 + rr];
      s0 += v0; q0 += v0 * v0; n0 += v0 * inv;
      s1 += v1; q1 += v1 * v1; n1 += v1 * inv;
    }
    atomicAdd(&colsum[c], s0);      atomicAdd(&colsum[c + 256], s1);
    atomicAdd(&colsumsq[c], q0);    atomicAdd(&colsumsq[c + 256], q1);
    atomicAdd(&snorm[c], n0);       atomicAdd(&snorm[c + 256], n1);
    return;
  }

  const int tid = threadIdx.x;
  const int wid = tid >> 6, lane = tid & 63;
  const int wr = wid >> 1, wc = wid & 1;
  const int fr = lane & 15, s0l = lane >> 4, fq = lane >> 4;

  // XCD-chunked column-major triangle: XCD k (= raw%8) gets 260 consecutive t
  const int raw = blockIdx.x - NRIDER;               // 0..2079
  const int t = (raw & 7) * 260 + (raw >> 3);
  // column-major decode: t = bj(bj+1)/2 + bi, bi <= bj
  int bj = (int)((sqrtf(8.0f * (float)t + 1.0f) - 1.0f) * 0.5f);
  while (bj < NBLK - 1 && (bj + 1) * (bj + 2) / 2 <= t) ++bj;
  while (bj > 0 && bj * (bj + 1) / 2 > t) --bj;
  const int bi = t - bj * (bj + 1) / 2;
  const int rowA = bi * 128, rowB = bj * 128;

  // ---- staging source offsets (8 chunks of 1KB per wave, 32 total) ----
  // panel [128][64] fp16, 128B rows = 8 slots of 16B; phys_slot = logical ^ (row&7)
  uint32_t goff[8];
#pragma unroll
  for (int s = 0; s < 8; ++s) {
    int c = wid * 8 + s;                       // 0..31
    int p = c >> 4;                            // 0=A, 1=B
    int off = (c & 15) * 1024 + lane * 16;     // physical byte in 16KB panel
    int r = off >> 7;                          // row 0..127
    int sl = ((off >> 4) & 7) ^ (r & 7);       // logical 16B slot
    int Lb = (sl << 4) | (off & 15);           // logical byte in row
    uint32_t grow = (uint32_t)((p ? rowB : rowA) + r);
    goff[s] = grow * (uint32_t)DIM + (uint32_t)(Lb >> 1);
  }

  // ---- fragment read offsets ----
  const int x = fr & 7;
  const int slk0 = ((s0l) ^ x) << 4;           // ks=0: logical slot s0l
  const int slk1 = ((4 + s0l) ^ x) << 4;       // ks=1: logical slot 4+s0l
  const int abase = (wr * 64 + fr) * 128;      // + m*2048 + slk
  const int bbase = 16384 + (wc * 64 + fr) * 128;

  f32x4 acc[4][4];
#pragma unroll
  for (int m = 0; m < 4; ++m)
#pragma unroll
    for (int n = 0; n < 4; ++n) acc[m][n] = (f32x4){0.f, 0.f, 0.f, 0.f};

  // ---- main loop: 8 K-steps of BK=64, single buffer ----
  for (int kt = 0; kt < 8; ++kt) {
    if (kt) __syncthreads();
#pragma unroll
    for (int s = 0; s < 8; ++s) {
      int c = wid * 8 + s;
      gload_lds16(zf + goff[s] + kt * 64,
                  (char*)lds + (c >> 4) * 16384 + (c & 15) * 1024);
    }
    __syncthreads();   // drains vmcnt + barrier: tile resident

#pragma unroll
    for (int ks = 0; ks < 2; ++ks) {
      const int slk = ks ? slk1 : slk0;
      f16x8 a[4], b[4];
#pragma unroll
      for (int m = 0; m < 4; ++m)
        a[m] = *(const f16x8*)((const char*)lds + abase + m * 2048 + slk);
#pragma unroll
      for (int n = 0; n < 4; ++n)
        b[n] = *(const f16x8*)((const char*)lds + bbase + n * 2048 + slk);
#pragma unroll
      for (int m = 0; m < 4; ++m)
#pragma unroll
        for (int n = 0; n < 4; ++n)
          acc[m][n] = __builtin_amdgcn_mfma_f32_16x16x32_f16(a[m], b[n], acc[m][n], 0, 0, 0);
    }
  }

  // ---- epilogue (r2-verified mapping) ----
  // row-side: rows gi in A-panel, reduce across 16 col-lanes (fr) + n
#pragma unroll
  for (int m = 0; m < 4; ++m) {
#pragma unroll
    for (int rr = 0; rr < 4; ++rr) {
      int gi = rowA + wr * 64 + m * 16 + fq * 4 + rr;
      float se = 0.f;
      unsigned long long best = 0ull;
#pragma unroll
      for (int n = 0; n < 4; ++n) {
        int gj = rowB + wc * 64 + n * 16 + fr;
        if (gi != gj) {
          float logit = 2.0f * acc[m][n][rr];   // /T with T=0.5
          se += __expf(logit);
          uint32_t bu = __float_as_uint(logit);
          uint32_t sk = (bu & 0x80000000u) ? ~bu : (bu | 0x80000000u);
          unsigned long long pk =
              ((unsigned long long)sk << 32) | (uint32_t)(~(uint32_t)gj);
          if (pk > best) best = pk;
        }
      }
#pragma unroll
      for (int msk = 1; msk < 16; msk <<= 1) {
        se += __shfl_xor(se, msk, 64);
        unsigned long long o = __shfl_xor(best, msk, 64);
        if (o > best) best = o;
      }
      if (fr == 0) {
        atomicAdd(&sumexp[gi], se);
        atomicMax(&amax[gi], best);
      }
    }
  }

  // col-side (off-diagonal only): rows gj in B-panel via cos^T = cos
  if (bi != bj) {
#pragma unroll
    for (int n = 0; n < 4; ++n) {
      int gj = rowB + wc * 64 + n * 16 + fr;
      float se = 0.f;
      unsigned long long best = 0ull;
#pragma unroll
      for (int m = 0; m < 4; ++m) {
#pragma unroll
        for (int rr = 0; rr < 4; ++rr) {
          int gi = rowA + wr * 64 + m * 16 + fq * 4 + rr;
          float logit = 2.0f * acc[m][n][rr];
          se += __expf(logit);
          uint32_t bu = __float_as_uint(logit);
          uint32_t sk = (bu & 0x80000000u) ? ~bu : (bu | 0x80000000u);
          unsigned long long pk =
              ((unsigned long long)sk << 32) | (uint32_t)(~(uint32_t)gi);
          if (pk > best) best = pk;
        }
      }
#pragma unroll
      for (int msk = 16; msk < 64; msk <<= 1) {
        se += __shfl_xor(se, msk, 64);
        unsigned long long o = __shfl_xor(best, msk, 64);
        if (o > best) best = o;
      }
      if (fq == 0) {
        atomicAdd(&sumexp[gj], se);
        atomicMax(&amax[gj], best);
      }
    }
  }
}

// ---------------- final combine ----------------
extern "C" __global__ __launch_bounds__(1024) void k_final(
    const float* __restrict__ sumexp, const unsigned long long* __restrict__ amax,
    const float* __restrict__ colsum, const float* __restrict__ colsumsq,
    const float* __restrict__ snorm, const float* __restrict__ partials,
    float* __restrict__ out)
{
  __shared__ double red[1024];
  const int t = threadIdx.x;
  double lsesum = 0.0, cnt = 0.0;
  for (int r = t; r < NROWS; r += 1024) {
    lsesum += log((double)sumexp[r]);
    int label = (r < BHALF) ? r + BHALF : r - BHALF;
    unsigned int idx = ~(unsigned int)(amax[r] & 0xffffffffull);
    if ((int)idx == label) cnt += 1.0;
  }
  double stdsum = 0, mn2 = 0, sn2 = 0;
  for (int c = t; c < DIM; c += 1024) {
    double su = colsum[c], sq = colsumsq[c];
    double var = (sq - su * su / 8192.0) / 8191.0;
    stdsum += sqrt(var > 0.0 ? var : 0.0);
    double m = su / 8192.0; mn2 += m * m;
    double s = snorm[c];   sn2 += s * s;
  }
  double trp = 0.0, pdp = 0.0;
  if (t < 1024) {
    trp = partials[t * 2];
    pdp = partials[t * 2 + 1];
  }
  auto red_sum = [&](double v) -> double {
    __syncthreads();
    red[t] = v; __syncthreads();
    for (int s = 512; s > 0; s >>= 1) {
      if (t < s) red[t] += red[t + s];
      __syncthreads();
    }
    return red[0];
  };
  double Tlse = red_sum(lsesum);
  double Tcnt = red_sum(cnt);
  double Tstd = red_sum(stdsum);
  double Tmn2 = red_sum(mn2);
  double Tsn2 = red_sum(sn2);
  double Ttr  = red_sum(trp);
  double Tpd  = red_sum(pdp);
  if (t == 0) {
    double pos_sim = Tpd / 4096.0;
    out[0] = (float)(Tlse / 8192.0 - 2.0 * pos_sim);
    out[1] = (float)(Tcnt / 8192.0);
    out[2] = (float)pos_sim;
    out[3] = (float)((Tsn2 - Ttr) / (8192.0 * 8191.0));
    out[4] = (float)(Tstd / 512.0);
    out[5] = (float)sqrt(Tmn2);
  }
}

extern "C" void kernel_launch(void* const* d_in, const int* in_sizes, int n_in,
                              void* d_out, int out_size, void* d_ws, size_t ws_size,
                              hipStream_t stream) {
  const float* za = (const float*)d_in[0];
  const float* zp = (const float*)d_in[1];
  float* out = (float*)d_out;
  char* ws = (char*)d_ws;
  size_t off = 0;
  unsigned short* zf = (unsigned short*)(ws + off); off += (size_t)NROWS * DIM * 2;
  float* inv_norms = (float*)(ws + off); off += (size_t)NROWS * 4;
  char* zbase = ws + off;                              // zero-init'd by k_prep
  float* sumexp = (float*)(ws + off); off += (size_t)NROWS * 4;
  unsigned long long* amax = (unsigned long long*)(ws + off); off += (size_t)NROWS * 8;
  float* colsum = (float*)(ws + off); off += (size_t)DIM * 4;
  float* colsumsq = (float*)(ws + off); off += (size_t)DIM * 4;
  float* snorm = (float*)(ws + off); off += (size_t)DIM * 4;
  float* partials = (float*)(ws + off); off += 2048 * 4;

  k_prep<<<dim3(1024), dim3(256), 0, stream>>>(za, zp, zf, inv_norms,
                                               partials, (uint32_t*)zbase);
  k_gemm<<<dim3(NTRI + NRIDER), dim3(256), 0, stream>>>(
      zf, za, zp, inv_norms, sumexp, amax, colsum, colsumsq, snorm);
  k_final<<<dim3(1), dim3(1024), 0, stream>>>(sumexp, amax, colsum, colsumsq,
                                              snorm, partials, out);
}